// Round 4
// baseline (233.687 us; speedup 1.0000x reference)
//
#include <hip/hip_runtime.h>

#define B_ 4
#define S_ 4096
#define T_ 4096
#define NH_ 16
#define SLICE 256          // s-elements per wave-slice
#define NSB 16             // slices per column (4096/256)

typedef unsigned long long u64;

__device__ __forceinline__ void ce(u64 &x, u64 &y) {   // after: x=min, y=max
    bool c = x < y;
    u64 t = x;
    x = c ? x : y;
    y = c ? y : t;
}
__device__ __forceinline__ void cemin(u64 &x, u64 y) { // x = min(x,y)
    x = x < y ? x : y;
}

// ---------------- Kernel A: sliced top-16 scan, bitonic batch updates ----------------
// grid = 64 column-supergroups x 16 slices = 1024 blocks x 256 threads.
// A block's 4 waves cover 256 CONSECUTIVE t of the SAME s-slice -> at each s-row the
// block touches one contiguous 1KB chunk (DRAM row-buffer friendly), not 4 scattered
// 256B chunks 4KB apart as before.
__global__ __launch_bounds__(256, 4) void topk_scan(
    const float* __restrict__ coords,   // [2][B][S][T]
    float* __restrict__ pv,             // [4096 waves][NH][64] partial d2, ascending
    unsigned short* __restrict__ pi)    // [4096 waves][NH][64] partial idx
{
    const int bid = blockIdx.x;
    const int ic  = threadIdx.x >> 6;         // column subgroup within block
    const int itl = threadIdx.x & 63;
    const int cg  = (bid >> 4) * 4 + ic;      // global 64-column group [0,256)
    const int sb  = bid & 15;                 // s-slice [0,16)
    const int ib  = cg >> 6;
    const int t   = (cg & 63) * 64 + itl;
    const int s0  = sb * SLICE;

    const size_t plane = (size_t)B_ * S_ * T_;
    const float* q0 = coords + (size_t)ib * S_ * T_ + (size_t)s0 * T_ + t;
    const float* q1 = q0 + plane;

    u64 l[16];
#pragma unroll
    for (int j = 0; j < 16; ++j) l[j] = ((u64)0x7f800000u << 32);

#pragma unroll 1
    for (int ss = 0; ss < SLICE; ss += 8) {
        float dx[8], dy[8];
#pragma unroll
        for (int u = 0; u < 8; ++u) {
            dx[u] = q0[(size_t)(ss + u) * T_];
            dy[u] = q1[(size_t)(ss + u) * T_];
        }
        u64 a[8];
#pragma unroll
        for (int u = 0; u < 8; ++u) {
            float d2 = dx[u] * dx[u] + dy[u] * dy[u];
            a[u] = ((u64)__float_as_uint(d2) << 32) | (unsigned)(s0 + ss + u);
        }
        // ---- sort8 ascending (Batcher, 19 CE) ----
        ce(a[0],a[1]); ce(a[2],a[3]); ce(a[0],a[2]); ce(a[1],a[3]); ce(a[1],a[2]);
        ce(a[4],a[5]); ce(a[6],a[7]); ce(a[4],a[6]); ce(a[5],a[7]); ce(a[5],a[6]);
        ce(a[0],a[4]); ce(a[1],a[5]); ce(a[2],a[6]); ce(a[3],a[7]);
        ce(a[2],a[4]); ce(a[3],a[5]);
        ce(a[1],a[2]); ce(a[3],a[4]); ce(a[5],a[6]);
        // ---- select: lower half of bitonic split of (l asc ++ rev(a)++inf) ----
#pragma unroll
        for (int j = 0; j < 8; ++j) cemin(l[8 + j], a[7 - j]);
        // ---- bitonic merge 16 (l is bitonic) ----
#pragma unroll
        for (int i = 0; i < 8; ++i) ce(l[i], l[i + 8]);
        ce(l[0],l[4]); ce(l[1],l[5]); ce(l[2],l[6]); ce(l[3],l[7]);
        ce(l[8],l[12]); ce(l[9],l[13]); ce(l[10],l[14]); ce(l[11],l[15]);
        ce(l[0],l[2]); ce(l[1],l[3]); ce(l[4],l[6]); ce(l[5],l[7]);
        ce(l[8],l[10]); ce(l[9],l[11]); ce(l[12],l[14]); ce(l[13],l[15]);
        ce(l[0],l[1]); ce(l[2],l[3]); ce(l[4],l[5]); ce(l[6],l[7]);
        ce(l[8],l[9]); ce(l[10],l[11]); ce(l[12],l[13]); ce(l[14],l[15]);
    }

    // store partial list: wave id w = cg*16+sb; layout [w][j][64] -> coalesced
    const int w = cg * NSB + sb;
#pragma unroll
    for (int j = 0; j < 16; ++j) {
        pv[((size_t)w * NH_ + j) * 64 + itl] = __uint_as_float((unsigned)(l[j] >> 32));
        pi[((size_t)w * NH_ + j) * 64 + itl] = (unsigned short)(l[j] & 0xFFFFu);
    }
}

// ---------------- Kernel B: merge 16 partial lists per column ----------------
__global__ __launch_bounds__(256) void topk_merge(
    const float* __restrict__ pv, const unsigned short* __restrict__ pi,
    float* __restrict__ outW,           // [B][T][NH]
    int*   __restrict__ outI)
{
    const int c   = blockIdx.x * 256 + threadIdx.x;  // [0, B*T)
    const int cg  = c >> 6;
    const int itl = c & 63;

    float cv[NH_]; int ci[NH_];
#pragma unroll
    for (int j = 0; j < NH_; ++j) { cv[j] = __int_as_float(0x7f800000); ci[j] = 0; }

    for (int sb = 0; sb < NSB; ++sb) {
        const size_t base = ((size_t)(cg * NSB + sb) * NH_) * 64 + itl;
        for (int j = 0; j < NH_; ++j) {
            float v = pv[base + (size_t)j * 64];
            if (!(v < cv[NH_ - 1])) break;       // ascending slices: stable ties
            int vi = (int)pi[base + (size_t)j * 64];
#pragma unroll
            for (int k = 0; k < NH_; ++k) {
                bool sw = v < cv[k];
                float tv = cv[k]; int ti = ci[k];
                cv[k] = sw ? v : tv;  ci[k] = sw ? vi : ti;
                v = sw ? tv : v;      vi = sw ? ti : vi;
            }
        }
    }

    const size_t base = (size_t)c * NH_;
#pragma unroll
    for (int j = 0; j < NH_; ++j) {
        float d = sqrtf(cv[j]) + 1e-15f;
        outW[base + j] = 1.0f / (d * d);
        outI[base + j] = ci[j];
    }
}

// ---------------- Kernel C: denom[b][nh] = sum_t w ----------------
__global__ __launch_bounds__(256) void denom_kernel(
    const float* __restrict__ outW, float* __restrict__ denom)
{
    const int ib = blockIdx.x >> 4;
    const int ih = blockIdx.x & 15;
    __shared__ float red[256];
    float acc = 0.f;
    for (int it = threadIdx.x; it < T_; it += 256)
        acc += outW[((size_t)ib * T_ + it) * NH_ + ih];
    red[threadIdx.x] = acc;
    __syncthreads();
    for (int s = 128; s > 0; s >>= 1) {
        if (threadIdx.x < s) red[threadIdx.x] += red[threadIdx.x + s];
        __syncthreads();
    }
    if (threadIdx.x == 0) denom[blockIdx.x] = red[0];
}

// ---------------- Kernel D: final gather + weighted sum ----------------
__global__ __launch_bounds__(256) void out_kernel(
    const float* __restrict__ x,        // [B][S]
    const float* __restrict__ outW,
    const int*   __restrict__ outI,
    const float* __restrict__ denom,    // [B][NH]
    float* __restrict__ out)            // [B][T]
{
    const int gid = blockIdx.x * 256 + threadIdx.x;
    const int i = gid >> 12;
    const int j = gid & 4095;
    const int ih = j >> 8;
    const size_t base = ((size_t)i * T_ + (size_t)(j & 255) * NH_) * NH_ + ih;
    const int dq = (j & 3) * NH_;
    float acc = 0.f;
#pragma unroll
    for (int k = 0; k < NH_; ++k) {
        float w  = outW[base + (size_t)k * NH_];
        int   id = outI[base + (size_t)k * NH_];
        acc += x[i * S_ + id] * w / denom[dq + k];
    }
    out[gid] = acc;
}

extern "C" void kernel_launch(void* const* d_in, const int* in_sizes, int n_in,
                              void* d_out, int out_size, void* d_ws, size_t ws_size,
                              hipStream_t stream) {
    const float* x      = (const float*)d_in[0];
    const float* coords = (const float*)d_in[1];
    float* out = (float*)d_out;

    const int nwaves = B_ * (T_ / 64) * NSB;                  // 4096 partial lists
    float*          pv    = (float*)d_ws;                                          // 16 MB
    unsigned short* pi    = (unsigned short*)(pv + (size_t)nwaves * NH_ * 64);     // 8 MB
    float*          outW  = (float*)(pi + (size_t)nwaves * NH_ * 64);              // 1 MB
    int*            outI  = (int*)(outW + (size_t)B_ * T_ * NH_);                  // 1 MB
    float*          denom = (float*)(outI + (size_t)B_ * T_ * NH_);                // 64 f32

    topk_scan   <<<64 * NSB,       256, 0, stream>>>(coords, pv, pi);
    topk_merge  <<<B_ * T_ / 256,  256, 0, stream>>>(pv, pi, outW, outI);
    denom_kernel<<<B_ * NH_,       256, 0, stream>>>(outW, denom);
    out_kernel  <<<B_ * T_ / 256,  256, 0, stream>>>(x, outW, outI, denom, out);
}

// Round 5
// 220.998 us; speedup vs baseline: 1.0574x; 1.0574x over previous
//
#include <hip/hip_runtime.h>

#define B_ 4
#define S_ 4096
#define T_ 4096
#define NH_ 16
#define CPB 16             // columns per block
#define CPW 4              // columns per wave
#define ROWS 64            // s-rows per LDS tile
#define NTILE (S_ / ROWS)  // 64
#define LDSP 17            // padded LDS row stride (dwords)

typedef unsigned long long u64;

// ---------------- Kernel A: transposed top-16 scan ----------------
// grid = B * (T/CPB) = 1024 blocks x 256 threads (4 waves).
// Block: 16 columns x all 4096 s. Tile [64 s][16 c] staged coalesced->LDS;
// each wave owns 4 columns; lanes = 64 s-elements of ONE column, so the
// "does this batch touch the top-16?" test is wave-uniform and almost always
// false -> hot path is ~8 instr per 64 elements; memory-bound.
__global__ __launch_bounds__(256, 4) void topk_scan(
    const float* __restrict__ coords,   // [2][B][S][T]
    float* __restrict__ outW,           // [B][T][NH]
    int*   __restrict__ outI,           // [B][T][NH]
    float* __restrict__ partials)       // [1024][NH] per-block denom partials
{
    __shared__ float lds0[ROWS * LDSP];
    __shared__ float lds1[ROWS * LDSP];
    __shared__ float red[4 * NH_];

    const int bid  = blockIdx.x;
    const int b    = bid >> 8;
    const int c0   = (bid & 255) * CPB;
    const int tid  = threadIdx.x;
    const int w    = tid >> 6;
    const int lane = tid & 63;

    const size_t plane = (size_t)B_ * S_ * T_;
    // staging map: wave w loads rows [w*16, w*16+16); lane -> row w*16+(lane>>2),
    // cols (lane&3)*4 .. +3 (one float4). 64B segments, coalesced.
    const int srow = w * 16 + (lane >> 2);
    const int scol = (lane & 3) * 4;
    const float* g0 = coords + (size_t)b * S_ * T_ + (size_t)srow * T_ + (c0 + scol);
    const float* g1 = g0 + plane;
    const int wbase = srow * LDSP + scol;

    // lane-distributed sorted lists: lane j (<16) holds slot j of each owned column
    float lv[CPW];
    int   li[CPW];
    float tau[CPW];
#pragma unroll
    for (int cc = 0; cc < CPW; ++cc) {
        lv[cc] = __int_as_float(0x7f800000);
        li[cc] = 0;
        tau[cc] = __int_as_float(0x7f800000);
    }

    // prologue: tile 0 into registers
    float4 a4 = *(const float4*)g0;
    float4 b4 = *(const float4*)g1;

    for (int k = 0; k < NTILE; ++k) {
        __syncthreads();                      // previous tile fully consumed
        lds0[wbase + 0] = a4.x; lds0[wbase + 1] = a4.y;
        lds0[wbase + 2] = a4.z; lds0[wbase + 3] = a4.w;
        lds1[wbase + 0] = b4.x; lds1[wbase + 1] = b4.y;
        lds1[wbase + 2] = b4.z; lds1[wbase + 3] = b4.w;
        if (k + 1 < NTILE) {                  // issue next tile's loads now;
            a4 = *(const float4*)(g0 + (size_t)(k + 1) * ROWS * T_);
            b4 = *(const float4*)(g1 + (size_t)(k + 1) * ROWS * T_);
        }
        __syncthreads();                      // tile k visible

#pragma unroll
        for (int cc = 0; cc < CPW; ++cc) {
            const int col = w * CPW + cc;
            const float dx = lds0[lane * LDSP + col];
            const float dy = lds1[lane * LDSP + col];
            const float d2 = dx * dx + dy * dy;
            u64 m = __ballot(d2 < tau[cc]);
            while (m) {                       // wave-uniform scalar loop
                const int src = __ffsll(m) - 1;   // lowest lane = smallest s (tie order)
                m &= m - 1;
                const float cd = __shfl(d2, src); // uniform src -> readlane
                const int   ci = k * ROWS + src;
                // insertion position among sorted slots (ties keep existing = smaller idx)
                const unsigned pm = (unsigned)__ballot(lv[cc] <= cd) & 0xFFFFu;
                const int p = __popc(pm);
                const float uv = __shfl_up(lv[cc], 1);
                const int   ui = __shfl_up(li[cc], 1);
                const bool here  = (lane == p);
                const bool shift = (lane > p) && (lane < NH_);
                lv[cc] = here ? cd : (shift ? uv : lv[cc]);
                li[cc] = here ? ci : (shift ? ui : li[cc]);
                tau[cc] = __shfl(lv[cc], NH_ - 1);
                m &= __ballot(d2 < tau[cc]);  // prune against tightened threshold
            }
        }
    }

    // epilogue: write lists + per-wave denom partials
    float dsum = 0.f;
#pragma unroll
    for (int cc = 0; cc < CPW; ++cc) {
        const int t = c0 + w * CPW + cc;
        if (lane < NH_) {
            const float d = sqrtf(lv[cc]) + 1e-15f;
            const float wv = 1.0f / (d * d);
            outW[((size_t)b * T_ + t) * NH_ + lane] = wv;
            outI[((size_t)b * T_ + t) * NH_ + lane] = li[cc];
            dsum += wv;
        }
    }
    if (lane < NH_) red[w * NH_ + lane] = dsum;
    __syncthreads();
    if (tid < NH_) {
        partials[(size_t)bid * NH_ + tid] =
            red[tid] + red[NH_ + tid] + red[2 * NH_ + tid] + red[3 * NH_ + tid];
    }
}

// ---------------- Kernel B: denom[b][nh] = sum of block partials ----------------
__global__ __launch_bounds__(64) void denom_reduce(
    const float* __restrict__ partials, float* __restrict__ denom)
{
    const int q = threadIdx.x;      // [0,64)
    const int b = q >> 4, j = q & 15;
    float s = 0.f;
    for (int g = 0; g < 256; ++g)
        s += partials[(size_t)(b * 256 + g) * NH_ + j];
    denom[q] = s;
}

// ---------------- Kernel C: final gather + weighted sum ----------------
__global__ __launch_bounds__(64) void out_kernel(
    const float* __restrict__ x,        // [B][S]
    const float* __restrict__ outW,
    const int*   __restrict__ outI,
    const float* __restrict__ denom,    // [B][NH]
    float* __restrict__ out)            // [B][T]
{
    const int gid = blockIdx.x * 64 + threadIdx.x;   // [0, B*T)
    const int i = gid >> 12;
    const int j = gid & 4095;
    const int ih = j >> 8;
    const size_t base = ((size_t)i * T_ + (size_t)(j & 255) * NH_) * NH_ + ih;
    const int dq = (j & 3) * NH_;
    float acc = 0.f;
#pragma unroll
    for (int k = 0; k < NH_; ++k) {
        float w  = outW[base + (size_t)k * NH_];
        int   id = outI[base + (size_t)k * NH_];
        acc += x[i * S_ + id] * w / denom[dq + k];
    }
    out[gid] = acc;
}

extern "C" void kernel_launch(void* const* d_in, const int* in_sizes, int n_in,
                              void* d_out, int out_size, void* d_ws, size_t ws_size,
                              hipStream_t stream) {
    const float* x      = (const float*)d_in[0];
    const float* coords = (const float*)d_in[1];
    float* out = (float*)d_out;

    float* outW     = (float*)d_ws;                                  // 1 MB
    int*   outI     = (int*)(outW + (size_t)B_ * T_ * NH_);          // 1 MB
    float* partials = (float*)(outI + (size_t)B_ * T_ * NH_);        // 64 KB
    float* denom    = partials + (size_t)1024 * NH_;                 // 256 B

    topk_scan   <<<B_ * (T_ / CPB), 256, 0, stream>>>(coords, outW, outI, partials);
    denom_reduce<<<1,               64,  0, stream>>>(partials, denom);
    out_kernel  <<<B_ * T_ / 64,    64,  0, stream>>>(x, outW, outI, denom, out);
}

// Round 6
// 155.301 us; speedup vs baseline: 1.5047x; 1.4230x over previous
//
#include <hip/hip_runtime.h>

#define B_ 4
#define S_ 4096
#define T_ 4096
#define NH_ 16
#define CPB 32             // columns per block = 128B rows (full cache lines)
#define CPW 2              // columns per wave (16 waves/block)
#define ROWS 64            // s-rows per LDS tile
#define NTILE (S_ / ROWS)  // 64
#define LDSP 33            // padded LDS row stride (dwords); odd -> bank permutation
#define NCG (T_ / CPB)     // 128 column groups

typedef unsigned long long u64;

// ---------------- Kernel A: transposed top-16 scan, high occupancy ----------------
// grid = B * NCG = 512 blocks x 1024 threads (16 waves) = 2 blocks/CU = 8 waves/SIMD.
// Block: 32 columns x all 4096 s. Tile [64 s][32 c]: threads 0-511 stage plane0,
// 512-1023 stage plane1 (one float4 each, 128B-line aligned rows). Wave w owns
// columns {2w, 2w+1}; lanes = 64 s-rows of one column -> ballot skip is per-column.
__global__ __launch_bounds__(1024, 8) void topk_scan(
    const float* __restrict__ coords,   // [2][B][S][T]
    float* __restrict__ outW,           // [B][T][NH]
    int*   __restrict__ outI,           // [B][T][NH]
    float* __restrict__ partials)       // [512][NH] per-block denom partials
{
    __shared__ float lds0[ROWS * LDSP];
    __shared__ float lds1[ROWS * LDSP];
    __shared__ float red[16 * NH_];

    const int bid  = blockIdx.x;
    const int b    = bid >> 7;
    const int c0   = (bid & (NCG - 1)) * CPB;
    const int tid  = threadIdx.x;
    const int w    = tid >> 6;
    const int lane = tid & 63;

    const size_t plane = (size_t)B_ * S_ * T_;
    // staging map: stid in [0,512): row = stid>>3 (64 rows), col4 = (stid&7)*4.
    // 8 consecutive threads = one 128B contiguous aligned line.
    const int stid = tid & 511;
    const int srow = stid >> 3;
    const int scol = (stid & 7) * 4;
    const float* gp = coords + (size_t)b * S_ * T_ + (size_t)srow * T_ + (c0 + scol)
                    + (tid >= 512 ? plane : (size_t)0);
    float* ldsw = (tid >= 512 ? lds1 : lds0) + srow * LDSP + scol;

    // lane-distributed sorted lists: lane j (<16) holds slot j of each owned column
    float lv[CPW]; int li[CPW]; float tau[CPW];
#pragma unroll
    for (int cc = 0; cc < CPW; ++cc) {
        lv[cc]  = __int_as_float(0x7f800000);
        li[cc]  = 0;
        tau[cc] = __int_as_float(0x7f800000);
    }

    // prologue: tile 0 into registers
    float4 v4 = *(const float4*)gp;

#pragma unroll 1
    for (int k = 0; k < NTILE; ++k) {
        __syncthreads();                      // previous tile fully consumed
        ldsw[0] = v4.x; ldsw[1] = v4.y; ldsw[2] = v4.z; ldsw[3] = v4.w;
        if (k + 1 < NTILE)                    // issue next tile's loads now
            v4 = *(const float4*)(gp + (size_t)(k + 1) * ROWS * T_);
        __syncthreads();                      // tile k visible

#pragma unroll
        for (int cc = 0; cc < CPW; ++cc) {
            const int col = w * CPW + cc;
            const float dx = lds0[lane * LDSP + col];
            const float dy = lds1[lane * LDSP + col];
            // uncontracted: bit-identical to np's cx*cx + cy*cy
            const float d2 = __fadd_rn(__fmul_rn(dx, dx), __fmul_rn(dy, dy));
            u64 m = __ballot(d2 < tau[cc]);
            while (m) {                       // wave-uniform scalar loop
                const int src = __ffsll(m) - 1;   // lowest lane = smallest s (tie order)
                m &= m - 1;
                const float cd = __shfl(d2, src); // uniform src -> readlane
                const int   ci = k * ROWS + src;
                // insertion position among sorted slots (ties keep existing = smaller idx)
                const unsigned pm = (unsigned)__ballot(lv[cc] <= cd) & 0xFFFFu;
                const int p = __popc(pm);
                const float uv = __shfl_up(lv[cc], 1);
                const int   ui = __shfl_up(li[cc], 1);
                const bool here  = (lane == p);
                const bool shift = (lane > p) && (lane < NH_);
                lv[cc] = here ? cd : (shift ? uv : lv[cc]);
                li[cc] = here ? ci : (shift ? ui : li[cc]);
                tau[cc] = __shfl(lv[cc], NH_ - 1);
                m &= __ballot(d2 < tau[cc]);  // prune vs tightened threshold
            }
        }
    }

    // epilogue: write lists + per-wave denom partials
    float dsum = 0.f;
#pragma unroll
    for (int cc = 0; cc < CPW; ++cc) {
        const int t = c0 + w * CPW + cc;
        if (lane < NH_) {
            const float d = sqrtf(lv[cc]) + 1e-15f;
            const float wv = 1.0f / (d * d);
            outW[((size_t)b * T_ + t) * NH_ + lane] = wv;
            outI[((size_t)b * T_ + t) * NH_ + lane] = li[cc];
            dsum += wv;
        }
    }
    if (lane < NH_) red[w * NH_ + lane] = dsum;
    __syncthreads();
    if (tid < NH_) {
        float s = 0.f;
#pragma unroll
        for (int q = 0; q < 16; ++q) s += red[q * NH_ + tid];
        partials[(size_t)bid * NH_ + tid] = s;
    }
}

// ---------------- Kernel B: denom[b][nh] = sum of block partials ----------------
__global__ __launch_bounds__(64) void denom_reduce(
    const float* __restrict__ partials, float* __restrict__ denom)
{
    const int q = threadIdx.x;      // [0,64)
    const int b = q >> 4, j = q & 15;
    float s = 0.f;
    for (int g = 0; g < NCG; ++g)
        s += partials[(size_t)(b * NCG + g) * NH_ + j];
    denom[q] = s;
}

// ---------------- Kernel C: final gather + weighted sum ----------------
__global__ __launch_bounds__(256) void out_kernel(
    const float* __restrict__ x,        // [B][S]
    const float* __restrict__ outW,
    const int*   __restrict__ outI,
    const float* __restrict__ denom,    // [B][NH]
    float* __restrict__ out)            // [B][T]
{
    const int gid = blockIdx.x * 256 + threadIdx.x;  // [0, B*T)
    const int i = gid >> 12;
    const int j = gid & 4095;
    const int ih = j >> 8;
    const size_t base = ((size_t)i * T_ + (size_t)(j & 255) * NH_) * NH_ + ih;
    const int dq = (j & 3) * NH_;
    float acc = 0.f;
#pragma unroll
    for (int k = 0; k < NH_; ++k) {
        float w  = outW[base + (size_t)k * NH_];
        int   id = outI[base + (size_t)k * NH_];
        acc += x[i * S_ + id] * w / denom[dq + k];
    }
    out[gid] = acc;
}

extern "C" void kernel_launch(void* const* d_in, const int* in_sizes, int n_in,
                              void* d_out, int out_size, void* d_ws, size_t ws_size,
                              hipStream_t stream) {
    const float* x      = (const float*)d_in[0];
    const float* coords = (const float*)d_in[1];
    float* out = (float*)d_out;

    float* outW     = (float*)d_ws;                                  // 1 MB
    int*   outI     = (int*)(outW + (size_t)B_ * T_ * NH_);          // 1 MB
    float* partials = (float*)(outI + (size_t)B_ * T_ * NH_);        // 32 KB
    float* denom    = partials + (size_t)(B_ * NCG) * NH_;           // 256 B

    topk_scan   <<<B_ * NCG,      1024, 0, stream>>>(coords, outW, outI, partials);
    denom_reduce<<<1,             64,   0, stream>>>(partials, denom);
    out_kernel  <<<B_ * T_ / 256, 256,  0, stream>>>(x, outW, outI, denom, out);
}

// Round 7
// 152.095 us; speedup vs baseline: 1.5364x; 1.0211x over previous
//
#include <hip/hip_runtime.h>

#define B_ 4
#define S_ 4096
#define T_ 4096
#define NH_ 16
#define CPB 32             // columns per block = 128B rows (full cache lines)
#define CPW 2              // columns per wave (16 waves/block)
#define ROWS 64            // s-rows per LDS tile
#define NTILE (S_ / ROWS)  // 64
#define LDSP 33            // padded LDS row stride (dwords); odd -> bank permutation
#define NCG (T_ / CPB)     // 128 column groups

typedef unsigned long long u64;

// ---------------- Kernel A: transposed top-16 scan, double-buffered ----------------
// grid = B * NCG = 512 blocks x 1024 threads (16 waves) = 2 blocks/CU = 8 waves/SIMD
// (32 waves/CU = HW cap). LDS double buffer: consume buf[k&1] while staging
// buf[(k+1)&1] and issuing the global load for tile k+2 -> ~2 tiles of latency
// cover, ONE barrier per tile.
__global__ __launch_bounds__(1024, 8) void topk_scan(
    const float* __restrict__ coords,   // [2][B][S][T]
    float* __restrict__ outW,           // [B][T][NH]
    int*   __restrict__ outI,           // [B][T][NH]
    float* __restrict__ partials)       // [512][NH] per-block denom partials
{
    __shared__ float lds[2][2][ROWS * LDSP];   // [buf][plane][row*LDSP+col]
    __shared__ float red[16 * NH_];

    const int bid  = blockIdx.x;
    const int b    = bid >> 7;
    const int c0   = (bid & (NCG - 1)) * CPB;
    const int tid  = threadIdx.x;
    const int w    = tid >> 6;
    const int lane = tid & 63;

    const size_t plane = (size_t)B_ * S_ * T_;
    // staging map: stid in [0,512): row = stid>>3, col4 = (stid&7)*4.
    // 8 consecutive threads = one 128B contiguous aligned line.
    const int stid = tid & 511;
    const int srow = stid >> 3;
    const int scol = (stid & 7) * 4;
    const int pl   = (tid >= 512) ? 1 : 0;
    const float* gp = coords + (size_t)b * S_ * T_ + (size_t)srow * T_ + (c0 + scol)
                    + (pl ? plane : (size_t)0);
    float* w0 = &lds[0][pl][srow * LDSP + scol];
    float* w1 = &lds[1][pl][srow * LDSP + scol];

    // lane-distributed sorted lists: lane j (<16) holds slot j of each owned column
    float lv[CPW]; int li[CPW]; float tau[CPW];
#pragma unroll
    for (int cc = 0; cc < CPW; ++cc) {
        lv[cc]  = __int_as_float(0x7f800000);
        li[cc]  = 0;
        tau[cc] = __int_as_float(0x7f800000);
    }

    // prologue: stage tile 0, prefetch tile 1 into registers
    float4 r4 = *(const float4*)gp;
    w0[0] = r4.x; w0[1] = r4.y; w0[2] = r4.z; w0[3] = r4.w;
    r4 = *(const float4*)(gp + (size_t)ROWS * T_);
    __syncthreads();                          // buf0 visible

#pragma unroll 1
    for (int k = 0; k < NTILE; ++k) {
        // stage tile k+1 (held in r4) into buf[(k+1)&1]; issue load of tile k+2
        if (k + 1 < NTILE) {
            float* wb = (k & 1) ? w0 : w1;
            wb[0] = r4.x; wb[1] = r4.y; wb[2] = r4.z; wb[3] = r4.w;
        }
        if (k + 2 < NTILE)
            r4 = *(const float4*)(gp + (size_t)(k + 2) * ROWS * T_);

        // consume tile k from buf[k&1]
        const float* rb0 = lds[k & 1][0];
        const float* rb1 = lds[k & 1][1];
#pragma unroll
        for (int cc = 0; cc < CPW; ++cc) {
            const int col = w * CPW + cc;
            const float dx = rb0[lane * LDSP + col];
            const float dy = rb1[lane * LDSP + col];
            // uncontracted: bit-identical to np's cx*cx + cy*cy
            const float d2 = __fadd_rn(__fmul_rn(dx, dx), __fmul_rn(dy, dy));
            u64 m = __ballot(d2 < tau[cc]);
            while (m) {                       // wave-uniform scalar loop
                const int src = __ffsll(m) - 1;   // lowest lane = smallest s (tie order)
                m &= m - 1;
                const float cd = __shfl(d2, src); // uniform src -> readlane
                const int   ci = k * ROWS + src;
                // insertion position among sorted slots (ties keep existing = smaller idx)
                const unsigned pm = (unsigned)__ballot(lv[cc] <= cd) & 0xFFFFu;
                const int p = __popc(pm);
                const float uv = __shfl_up(lv[cc], 1);
                const int   ui = __shfl_up(li[cc], 1);
                const bool here  = (lane == p);
                const bool shift = (lane > p) && (lane < NH_);
                lv[cc] = here ? cd : (shift ? uv : lv[cc]);
                li[cc] = here ? ci : (shift ? ui : li[cc]);
                tau[cc] = __shfl(lv[cc], NH_ - 1);
                m &= __ballot(d2 < tau[cc]);  // prune vs tightened threshold
            }
        }
        __syncthreads();                      // buf[(k+1)&1] staged; buf[k&1] free
    }

    // epilogue: write lists + per-wave denom partials
    float dsum = 0.f;
#pragma unroll
    for (int cc = 0; cc < CPW; ++cc) {
        const int t = c0 + w * CPW + cc;
        if (lane < NH_) {
            const float d = sqrtf(lv[cc]) + 1e-15f;
            const float wv = 1.0f / (d * d);
            outW[((size_t)b * T_ + t) * NH_ + lane] = wv;
            outI[((size_t)b * T_ + t) * NH_ + lane] = li[cc];
            dsum += wv;
        }
    }
    if (lane < NH_) red[w * NH_ + lane] = dsum;
    __syncthreads();
    if (tid < NH_) {
        float s = 0.f;
#pragma unroll
        for (int q = 0; q < 16; ++q) s += red[q * NH_ + tid];
        partials[(size_t)bid * NH_ + tid] = s;
    }
}

// ---------------- Kernel B: denom[b][nh] = sum of block partials ----------------
// grid = 64 blocks (one per (b,nh)) x 128 threads tree-reduce over NCG partials.
__global__ __launch_bounds__(128) void denom_reduce(
    const float* __restrict__ partials, float* __restrict__ denom)
{
    const int q = blockIdx.x;       // [0,64)
    const int b = q >> 4, j = q & 15;
    const int g = threadIdx.x;      // [0,128) = NCG
    __shared__ float sm[128];
    sm[g] = partials[(size_t)(b * NCG + g) * NH_ + j];
    __syncthreads();
    for (int s = 64; s > 0; s >>= 1) {
        if (g < s) sm[g] += sm[g + s];
        __syncthreads();
    }
    if (g == 0) denom[q] = sm[0];
}

// ---------------- Kernel C: final gather + weighted sum ----------------
__global__ __launch_bounds__(256) void out_kernel(
    const float* __restrict__ x,        // [B][S]
    const float* __restrict__ outW,
    const int*   __restrict__ outI,
    const float* __restrict__ denom,    // [B][NH]
    float* __restrict__ out)            // [B][T]
{
    const int gid = blockIdx.x * 256 + threadIdx.x;  // [0, B*T)
    const int i = gid >> 12;
    const int j = gid & 4095;
    const int ih = j >> 8;
    const size_t base = ((size_t)i * T_ + (size_t)(j & 255) * NH_) * NH_ + ih;
    const int dq = (j & 3) * NH_;
    float acc = 0.f;
#pragma unroll
    for (int k = 0; k < NH_; ++k) {
        float w  = outW[base + (size_t)k * NH_];
        int   id = outI[base + (size_t)k * NH_];
        acc += x[i * S_ + id] * w / denom[dq + k];
    }
    out[gid] = acc;
}

extern "C" void kernel_launch(void* const* d_in, const int* in_sizes, int n_in,
                              void* d_out, int out_size, void* d_ws, size_t ws_size,
                              hipStream_t stream) {
    const float* x      = (const float*)d_in[0];
    const float* coords = (const float*)d_in[1];
    float* out = (float*)d_out;

    float* outW     = (float*)d_ws;                                  // 1 MB
    int*   outI     = (int*)(outW + (size_t)B_ * T_ * NH_);          // 1 MB
    float* partials = (float*)(outI + (size_t)B_ * T_ * NH_);        // 32 KB
    float* denom    = partials + (size_t)(B_ * NCG) * NH_;           // 256 B

    topk_scan   <<<B_ * NCG,      1024, 0, stream>>>(coords, outW, outI, partials);
    denom_reduce<<<64,            128,  0, stream>>>(partials, denom);
    out_kernel  <<<B_ * T_ / 256, 256,  0, stream>>>(x, outW, outI, denom, out);
}